// Round 1
// baseline (564.309 us; speedup 1.0000x reference)
//
#include <hip/hip_runtime.h>
#include <hip/hip_bf16.h>

typedef unsigned short u16;
typedef unsigned int u32;
typedef __bf16 bf16x8 __attribute__((ext_vector_type(8)));
typedef float f32x4 __attribute__((ext_vector_type(4)));

// B=65536, I=64, H=64, T=16, G=3H=192

__device__ __forceinline__ u16 f2bf(float f) {
  union { float f; u32 u; } v; v.f = f;
  u32 u = v.u;
  return (u16)((u + 0x7fffu + ((u >> 16) & 1u)) >> 16);  // RNE
}
__device__ __forceinline__ u32 pk2(float a, float b) {
  union { __hip_bfloat162 h; u32 u; } v;
  v.h = __float22bfloat162_rn(float2{a, b});   // v_cvt_pk_bf16_f32 on gfx950
  return v.u;
}
__device__ __forceinline__ bf16x8 pack8(float4 a, float4 b) {
  union { u32 u[4]; bf16x8 v; } r;
  r.u[0] = pk2(a.x, a.y); r.u[1] = pk2(a.z, a.w);
  r.u[2] = pk2(b.x, b.y); r.u[3] = pk2(b.z, b.w);
  return r.v;
}
__device__ __forceinline__ float sigf(float x) { return 1.0f / (1.0f + __expf(-x)); }
__device__ __forceinline__ float tanh_fast(float x) { return 2.0f * sigf(2.0f * x) - 1.0f; }

__device__ __forceinline__ void gl_lds16(const void* g, void* l) {
  __builtin_amdgcn_global_load_lds(
      (const __attribute__((address_space(1))) unsigned int*)g,
      (__attribute__((address_space(3))) unsigned int*)l, 16, 0, 0);
}

// ---------------- K0: weight convert + zero type counters ----------------
__global__ __launch_bounds__(256) void k0_convert(
    const float* __restrict__ Wih, const float* __restrict__ Whh,
    const float* __restrict__ cWih, const float* __restrict__ cWhh,
    u16* __restrict__ wih_bf, u16* __restrict__ whh_bf,
    u16* __restrict__ cwih_bf, u16* __restrict__ cwhh_bf, int* __restrict__ gcnt)
{
  int i = blockIdx.x * 256 + threadIdx.x;
  if (blockIdx.x == 0 && threadIdx.x < 16) gcnt[threadIdx.x] = 0;
  if (i < 196608) {
    wih_bf[i]  = f2bf(Wih[i]);
    whh_bf[i]  = f2bf(Whh[i]);
    cwih_bf[i] = f2bf(cWih[i]);
  }
  if (i < 12288) cwhh_bf[i] = f2bf(cWhh[i]);
}

// ---------------- KC: compact rows by type ----------------
__global__ __launch_bounds__(256) void k_compact(
    const int* __restrict__ typ, int* __restrict__ gcnt, int* __restrict__ lists)
{
  __shared__ int cnt[16], base[16];
  const int tid = threadIdx.x;
  if (tid < 16) cnt[tid] = 0;
  __syncthreads();
  int r = blockIdx.x * 256 + tid;
  int t = typ[r];
  int rank = atomicAdd(&cnt[t], 1);
  __syncthreads();
  if (tid < 16) base[tid] = atomicAdd(&gcnt[tid], cnt[tid]);
  __syncthreads();
  lists[(size_t)t * 65536 + base[t] + rank] = r;
}

// ---------------- K_FUSED: per-type GRU + delta-corrected core GEMM + core GRU ----------------
// Blocks own 64 type-sorted rows (uniform type t via lists). Per block:
//   1. type-GRU for its rows (weights direct from L2, as old k1) -> delta tile in LDS
//   2. cgh = c @ cWhh^T (scattered rows, direct from global)
//   3. correction chunk: agi += delta @ cWih[:, t*64:+64]^T   (fp32 accumulate, no corr round-trip)
//   4. 16-chunk main GEMM over regs (double-buffered global_load_lds, swizzled; B direct from L2)
//   5. fused core-GRU epilogue, scattered out writes
__global__ __launch_bounds__(256, 2) void k_fused(
    const float* __restrict__ x, const float* __restrict__ regs,
    const float* __restrict__ c,
    const u16* __restrict__ wih_bf, const u16* __restrict__ whh_bf,
    const float* __restrict__ bih, const float* __restrict__ bhh,
    const u16* __restrict__ cwih_bf, const u16* __restrict__ cwhh_bf,
    const float* __restrict__ cbih, const float* __restrict__ cbhh,
    const int* __restrict__ gcnt, const int* __restrict__ lists,
    float* __restrict__ out)
{
  const int t = blockIdx.y;
  const int cnt = gcnt[t];
  if ((int)blockIdx.x * 64 >= cnt) return;

  __shared__ __align__(16) float sA[2][4096];   // 64 rows x 64 f32, double-buffered (32 KB)
  __shared__ __align__(16) u16  sD[4096];       // 64x64 bf16 delta, group-swizzled (8 KB)
  __shared__ int s_rows[64];

  const int tid = threadIdx.x;
  const int lane = tid & 63;
  const int wv = tid >> 6;
  const int col = lane & 15;
  const int quad = lane >> 4;
  const int hidx = wv * 16 + col;
  const f32x4 zero = {0.f, 0.f, 0.f, 0.f};

  // type-persistent B fragments (L2-hot: shared by all blocks of this type)
  bf16x8 bw[3][2], bh[3][2], bc[3][2];
  float vbi[3], vbh[3];
#pragma unroll
  for (int g = 0; g < 3; ++g) {
    const u16* pw = wih_bf + ((size_t)t * 192 + g * 64 + hidx) * 64;
    const u16* ph = whh_bf + ((size_t)t * 192 + g * 64 + hidx) * 64;
    const u16* pc = cwih_bf + (size_t)(g * 64 + hidx) * 1024 + t * 64;
#pragma unroll
    for (int ks = 0; ks < 2; ++ks) {
      bw[g][ks] = *(const bf16x8*)(pw + ks * 32 + quad * 8);
      bh[g][ks] = *(const bf16x8*)(ph + ks * 32 + quad * 8);
      bc[g][ks] = *(const bf16x8*)(pc + ks * 32 + quad * 8);
    }
    vbi[g] = bih[t * 192 + g * 64 + hidx];
    vbh[g] = bhh[t * 192 + g * 64 + hidx];
  }
  const float e0 = cbih[hidx], e1 = cbih[64 + hidx], e2 = cbih[128 + hidx];
  const float d0 = cbhh[hidx], d1 = cbhh[64 + hidx], d2 = cbhh[128 + hidx];

  for (int tile = blockIdx.x; tile * 64 < cnt; tile += (int)gridDim.x) {
    __syncthreads();   // protect s_rows/sA/sD reuse across tile iterations
    if (tid < 64) {
      int idx = tile * 64 + tid;
      s_rows[tid] = lists[(size_t)t * 65536 + (idx < cnt ? idx : cnt - 1)];
    }
    __syncthreads();

    // per-thread staging base pointers; r = s*16 + wv*4 + quad, so (r&15) is s-invariant
    const int grp = lane & 15;
    const int rsw = wv * 4 + quad;
    const float* pA[4];
#pragma unroll
    for (int s = 0; s < 4; ++s)
      pA[s] = regs + (size_t)s_rows[s * 16 + wv * 4 + quad] * 1024 + ((grp ^ rsw) << 2);

    // stage chunk 0 (latency hides under the GRU below)
#pragma unroll
    for (int s = 0; s < 4; ++s)
      gl_lds16(pA[s], &sA[0][(s * 4 + wv) * 256]);

    // ---- per-type GRU -> delta tile (bf16, swizzled by 8-element group) ----
#pragma unroll 2
    for (int mt = 0; mt < 4; ++mt) {
      const int ra = s_rows[mt * 16 + col];
      f32x4 agi1[3], agh1[3];
#pragma unroll
      for (int g = 0; g < 3; ++g) { agi1[g] = zero; agh1[g] = zero; }
#pragma unroll
      for (int ks = 0; ks < 2; ++ks) {
        const float* xr = x + (size_t)ra * 64 + ks * 32 + quad * 8;
        const float* hr = regs + (size_t)ra * 1024 + t * 64 + ks * 32 + quad * 8;
        bf16x8 ax = pack8(*(const float4*)xr, *(const float4*)(xr + 4));
        bf16x8 ah = pack8(*(const float4*)hr, *(const float4*)(hr + 4));
#pragma unroll
        for (int g = 0; g < 3; ++g) {
          agi1[g] = __builtin_amdgcn_mfma_f32_16x16x32_bf16(ax, bw[g][ks], agi1[g], 0, 0, 0);
          agh1[g] = __builtin_amdgcn_mfma_f32_16x16x32_bf16(ah, bh[g][ks], agh1[g], 0, 0, 0);
        }
      }
#pragma unroll
      for (int rr = 0; rr < 4; ++rr) {
        const int m = mt * 16 + quad * 4 + rr;
        const int r2 = s_rows[m];
        float ir  = agi1[0][rr] + vbi[0];
        float iz  = agi1[1][rr] + vbi[1];
        float in_ = agi1[2][rr] + vbi[2];
        float hr2 = agh1[0][rr] + vbh[0];
        float hz  = agh1[1][rr] + vbh[1];
        float hn  = agh1[2][rr] + vbh[2];
        float rg = sigf(ir + hr2);
        float zg = sigf(iz + hz);
        float ng = tanh_fast(in_ + rg * hn);
        float hold = regs[(size_t)r2 * 1024 + t * 64 + hidx];
        float hnew = (1.f - zg) * ng + zg * hold;
        sD[m * 64 + (((hidx >> 3) ^ (m & 7)) << 3) + (hidx & 7)] = f2bf(hnew - hold);
      }
    }

    // ---- cgh = c @ cWhh^T (K=64), scattered rows, direct from global ----
    f32x4 agh[4][3];
#pragma unroll
    for (int mt = 0; mt < 4; ++mt)
#pragma unroll
      for (int g = 0; g < 3; ++g) agh[mt][g] = zero;
#pragma unroll
    for (int ks = 0; ks < 2; ++ks) {
      bf16x8 bh2[3];
#pragma unroll
      for (int g = 0; g < 3; ++g)
        bh2[g] = *(const bf16x8*)(cwhh_bf + (size_t)(g * 64 + hidx) * 64 + ks * 32 + quad * 8);
#pragma unroll
      for (int mt = 0; mt < 4; ++mt) {
        const float* cr = c + (size_t)s_rows[mt * 16 + col] * 64 + ks * 32 + quad * 8;
        bf16x8 af = pack8(*(const float4*)cr, *(const float4*)(cr + 4));
#pragma unroll
        for (int g = 0; g < 3; ++g)
          agh[mt][g] = __builtin_amdgcn_mfma_f32_16x16x32_bf16(af, bh2[g], agh[mt][g], 0, 0, 0);
      }
    }

    __syncthreads();   // sD complete; chunk-0 stage drained (compiler vmcnt(0) before barrier)

    // ---- delta-correction chunk: agi += delta @ bc^T (fp32 accumulate) ----
    f32x4 agi[4][3];
#pragma unroll
    for (int mt = 0; mt < 4; ++mt)
#pragma unroll
      for (int g = 0; g < 3; ++g) agi[mt][g] = zero;
#pragma unroll
    for (int ks = 0; ks < 2; ++ks) {
#pragma unroll
      for (int mt = 0; mt < 4; ++mt) {
        const int m = mt * 16 + col;
        bf16x8 ad = *(const bf16x8*)(&sD[m * 64 + (((ks * 4 + quad) ^ (m & 7)) << 3)]);
#pragma unroll
        for (int g = 0; g < 3; ++g)
          agi[mt][g] = __builtin_amdgcn_mfma_f32_16x16x32_bf16(ad, bc[g][ks], agi[mt][g], 0, 0, 0);
      }
    }

    // ---- main GEMM: 16 K-chunks over regs; B fragments direct from L2 ----
    for (int kc = 0; kc < 16; ++kc) {
      __syncthreads();
      if (kc < 15) {
        float* sAn = sA[(kc + 1) & 1];
#pragma unroll
        for (int s = 0; s < 4; ++s)
          gl_lds16(pA[s] + (kc + 1) * 64, sAn + (s * 4 + wv) * 256);
      }
      const float* sAc = sA[kc & 1];
#pragma unroll
      for (int ks = 0; ks < 2; ++ks) {
        bf16x8 bfr[3];
#pragma unroll
        for (int g = 0; g < 3; ++g)
          bfr[g] = *(const bf16x8*)(cwih_bf + (size_t)(g * 64 + hidx) * 1024 + kc * 64 + ks * 32 + quad * 8);
#pragma unroll
        for (int mt = 0; mt < 4; ++mt) {
          const int r = mt * 16 + col;
          const int g0 = ks * 8 + quad * 2;
          float4 q0 = *(const float4*)(sAc + r * 64 + (((g0    ) ^ (r & 15)) << 2));
          float4 q1 = *(const float4*)(sAc + r * 64 + (((g0 + 1) ^ (r & 15)) << 2));
          bf16x8 af = pack8(q0, q1);
#pragma unroll
          for (int g = 0; g < 3; ++g)
            agi[mt][g] = __builtin_amdgcn_mfma_f32_16x16x32_bf16(af, bfr[g], agi[mt][g], 0, 0, 0);
        }
      }
    }

    // ---- fused core-GRU epilogue (scattered rows, masked for list padding) ----
#pragma unroll
    for (int mt = 0; mt < 4; ++mt) {
#pragma unroll
      for (int rr = 0; rr < 4; ++rr) {
        const int m = mt * 16 + quad * 4 + rr;
        if (tile * 64 + m < cnt) {
          const size_t b = (size_t)s_rows[m];
          float ir  = agi[mt][0][rr] + e0;
          float iz  = agi[mt][1][rr] + e1;
          float in_ = agi[mt][2][rr] + e2;
          float hr2 = agh[mt][0][rr] + d0;
          float hz  = agh[mt][1][rr] + d1;
          float hn  = agh[mt][2][rr] + d2;
          float rg = sigf(ir + hr2);
          float zg = sigf(iz + hz);
          float ng = tanh_fast(in_ + rg * hn);
          float cold = c[b * 64 + hidx];
          out[b * 64 + hidx] = (1.f - zg) * ng + zg * cold;
        }
      }
    }
  }
}

extern "C" void kernel_launch(void* const* d_in, const int* in_sizes, int n_in,
                              void* d_out, int out_size, void* d_ws, size_t ws_size,
                              hipStream_t stream) {
  const float* x    = (const float*)d_in[0];
  const int*   typ  = (const int*)d_in[1];
  const float* c    = (const float*)d_in[2];
  const float* regs = (const float*)d_in[3];
  const float* Wih  = (const float*)d_in[4];
  const float* Whh  = (const float*)d_in[5];
  const float* bih  = (const float*)d_in[6];
  const float* bhh  = (const float*)d_in[7];
  const float* cWih = (const float*)d_in[8];
  const float* cWhh = (const float*)d_in[9];
  const float* cbih = (const float*)d_in[10];
  const float* cbhh = (const float*)d_in[11];
  float* out = (float*)d_out;

  char* ws = (char*)d_ws;
  u16* wih_bf  = (u16*)(ws + 0);            // 393216 B
  u16* whh_bf  = (u16*)(ws + 393216);       // 393216 B
  u16* cwih_bf = (u16*)(ws + 786432);       // 393216 B
  u16* cwhh_bf = (u16*)(ws + 1179648);      // 24576 B
  int* gcnt    = (int*)(ws + 1204224);      // 64 B
  int* lists   = (int*)(ws + 1204288);      // 4 MB

  k0_convert<<<768, 256, 0, stream>>>(Wih, Whh, cWih, cWhh,
                                      wih_bf, whh_bf, cwih_bf, cwhh_bf, gcnt);
  k_compact<<<256, 256, 0, stream>>>(typ, gcnt, lists);
  // 72 tiles/type covers cnt up to 4608 (mean 4096, sigma ~62 -> +8 sigma);
  // grid-stride tile loop makes it safe for any count regardless.
  k_fused<<<dim3(72, 16), 256, 0, stream>>>(x, regs, c, wih_bf, whh_bf, bih, bhh,
                                            cwih_bf, cwhh_bf, cbih, cbhh, gcnt, lists, out);
}